// Round 1
// baseline (1520.399 us; speedup 1.0000x reference)
//
#include <hip/hip_runtime.h>
#include <hip/hip_bf16.h>
#include <math.h>

#define KPRE 512
#define CAP 4096
#define MAXDET 300
#define SCORE_THR 0.05f
#define IOU_THR 0.5f

// ---------------- Kernel A: per-anchor score (max over C) + label (argmax) --------------
__global__ void score_label_kernel(const float* __restrict__ cls,
                                   unsigned* __restrict__ keys,
                                   int* __restrict__ labels,
                                   int total, int C) {
    int i = blockIdx.x * blockDim.x + threadIdx.x;
    if (i >= total) return;
    const float4* p = (const float4*)(cls + (size_t)i * C);
    float best = -1e30f;
    int bi = 0;
    int C4 = C >> 2;
    for (int j = 0; j < C4; ++j) {
        float4 v = p[j];
        int j4 = j * 4;
        if (v.x > best) { best = v.x; bi = j4; }
        if (v.y > best) { best = v.y; bi = j4 + 1; }
        if (v.z > best) { best = v.z; bi = j4 + 2; }
        if (v.w > best) { best = v.w; bi = j4 + 3; }
    }
    // positive float -> bit pattern is order-preserving; 0 marks "below threshold"
    keys[i] = (best > SCORE_THR) ? __float_as_uint(best) : 0u;
    labels[i] = bi;
}

// ---------------- Kernel B: per-batch top-512 select + NMS + top-300 output ------------
__global__ __launch_bounds__(1024, 1)
void select_nms_kernel(const float* __restrict__ anchors,
                       const float* __restrict__ reg,
                       const float* __restrict__ sizes,
                       const unsigned* __restrict__ keys,
                       const int* __restrict__ labels,
                       float* __restrict__ out,
                       int N, int B) {
    const int b = blockIdx.x;
    const int tid = threadIdx.x;
    const int nthr = blockDim.x;
    const unsigned* kb = keys + (size_t)b * N;

    // buf (4096 x u64 = 32KB) aliased later as sup-bitmatrix (512 x 16 x u32 = 32KB)
    __shared__ unsigned long long buf[CAP];
    unsigned* sup = (unsigned*)buf;   // sup[i*16 + w]
    __shared__ unsigned hist[256];
    __shared__ float4 boxs[KPRE];
    __shared__ float areas[KPRE];
    __shared__ unsigned ckey[KPRE];
    __shared__ unsigned cidx[KPRE];
    __shared__ unsigned validw[16];
    __shared__ unsigned keepw_s[16];
    __shared__ unsigned wpref[17];
    __shared__ unsigned sh_cnt, sh_prefix;
    __shared__ int sh_k, sh_M;

    // ---- exact 512th-largest key via MSB-first radix select (8-bit digits) ----
    unsigned prefix = 0;
    int k = KPRE;
    for (int shift = 24; shift >= 0; shift -= 8) {
        for (int i2 = tid; i2 < 256; i2 += nthr) hist[i2] = 0;
        __syncthreads();
        unsigned pm = (shift == 24) ? 0u : (0xFFFFFFFFu << (shift + 8));
        unsigned pv = (shift == 24) ? 0u : (prefix << (shift + 8));
        for (int i2 = tid; i2 < N; i2 += nthr) {
            unsigned key = kb[i2];
            if ((key & pm) == pv) atomicAdd(&hist[(key >> shift) & 255], 1);
        }
        __syncthreads();
        if (tid == 0) {
            int acc = 0, d = 0;
            for (int bin = 255; bin >= 0; --bin) {
                int c = (int)hist[bin];
                if (acc + c >= k) { d = bin; break; }
                acc += c;
            }
            sh_prefix = (prefix << 8) | (unsigned)d;
            sh_k = k - acc;
        }
        __syncthreads();
        prefix = sh_prefix;
        k = sh_k;
    }
    const unsigned cutoff = prefix;   // exact 512th-largest key (or 0 if <512 valid)

    // ---- collect all keys >= cutoff (valid only) ----
    if (tid == 0) sh_cnt = 0;
    __syncthreads();
    for (int i2 = tid; i2 < N; i2 += nthr) {
        unsigned key = kb[i2];
        if (key != 0u && key >= cutoff) {
            unsigned p = atomicAdd(&sh_cnt, 1u);
            if (p < CAP)
                buf[p] = ((unsigned long long)key << 32) | (unsigned)(~(unsigned)i2);
        }
    }
    __syncthreads();
    int cnt = (int)sh_cnt; if (cnt > CAP) cnt = CAP;
    if (tid == 0) {
        int M = KPRE;
        while (M < cnt) M <<= 1;
        sh_M = M;
    }
    __syncthreads();
    const int M = sh_M;
    for (int i2 = cnt + tid; i2 < M; i2 += nthr) buf[i2] = 0ull;
    __syncthreads();

    // ---- bitonic sort descending: key desc, index asc (composite uses ~idx) ----
    for (int kk = 2; kk <= M; kk <<= 1) {
        for (int j = kk >> 1; j > 0; j >>= 1) {
            for (int i2 = tid; i2 < M; i2 += nthr) {
                int l = i2 ^ j;
                if (l > i2) {
                    unsigned long long a = buf[i2], c = buf[l];
                    bool desc = ((i2 & kk) == 0);
                    if (desc ? (a < c) : (a > c)) { buf[i2] = c; buf[l] = a; }
                }
            }
            __syncthreads();
        }
    }

    // ---- extract top-512 candidates; decode + clip boxes (reference formula) ----
    const float wimg = sizes[b * 2 + 1];
    const float himg = sizes[b * 2 + 0];
    for (int t = tid; t < KPRE; t += nthr) {
        unsigned long long c = buf[t];
        unsigned key = (unsigned)(c >> 32);
        unsigned ai = ~(unsigned)(c & 0xFFFFFFFFull);
        bool valid = (key != 0u) && (t < cnt);
        ckey[t] = valid ? key : 0u;
        cidx[t] = valid ? ai : 0u;
        float4 bx = make_float4(0.f, 0.f, 0.f, 0.f);
        if (valid) {
            const float4 a4 = *(const float4*)(anchors + ((size_t)b * N + ai) * 4);
            const float4 r4 = *(const float4*)(reg + ((size_t)b * N + ai) * 4);
            float w = a4.z - a4.x, h = a4.w - a4.y;
            float cx = a4.x + 0.5f * w, cy = a4.y + 0.5f * h;
            float dx = r4.x * 0.1f, dy = r4.y * 0.1f;
            float dw = r4.z * 0.2f, dh = r4.w * 0.2f;
            float pcx = cx + dx * w, pcy = cy + dy * h;
            float pw = expf(dw) * w, ph = expf(dh) * h;
            float x1 = pcx - 0.5f * pw, y1 = pcy - 0.5f * ph;
            float x2 = pcx + 0.5f * pw, y2 = pcy + 0.5f * ph;
            bx.x = fminf(fmaxf(x1, 0.f), wimg);
            bx.y = fminf(fmaxf(y1, 0.f), himg);
            bx.z = fminf(fmaxf(x2, 0.f), wimg);
            bx.w = fminf(fmaxf(y2, 0.f), himg);
        }
        boxs[t] = bx;
        areas[t] = (bx.z - bx.x) * (bx.w - bx.y);
    }
    __syncthreads();

    // ---- suppression bitmatrix: sup[i][w] bit b = (iou(i, w*32+b) > 0.5) && (j > i) ----
    for (int unit = tid; unit < KPRE * 16; unit += nthr) {
        int i = unit >> 4, w = unit & 15;
        float4 bi = boxs[i];
        float ai = areas[i];
        unsigned bits = 0;
        int j0 = w * 32;
        for (int bit = 0; bit < 32; ++bit) {
            int j = j0 + bit;
            if (j > i) {
                float4 bj = boxs[j];
                float ltx = fmaxf(bi.x, bj.x), lty = fmaxf(bi.y, bj.y);
                float rbx = fminf(bi.z, bj.z), rby = fminf(bi.w, bj.w);
                float iw = fmaxf(rbx - ltx, 0.f), ih = fmaxf(rby - lty, 0.f);
                float inter = iw * ih;
                float iou = inter / (ai + areas[j] - inter + 1e-9f);
                if (iou > IOU_THR) bits |= (1u << bit);
            }
        }
        sup[i * 16 + w] = bits;
    }
    __syncthreads();

    // ---- validity bitmask via per-wave ballot ----
    unsigned long long bal = __ballot(tid < KPRE && ckey[tid] != 0u);
    if (tid < KPRE && (tid & 63) == 0) {
        validw[(tid >> 6) * 2] = (unsigned)(bal & 0xFFFFFFFFull);
        validw[(tid >> 6) * 2 + 1] = (unsigned)(bal >> 32);
    }
    __syncthreads();

    // ---- single-wave greedy NMS scan: lane w holds keep-word w in a register ----
    if (tid < 64) {
        unsigned kw = (tid < 16) ? validw[tid] : 0u;
        for (int i = 0; i < KPRE; ++i) {
            unsigned rw = sup[i * 16 + (tid & 15)];   // prefetchable: address keep-independent
            unsigned ow = __shfl(kw, i >> 5, 64);
            if ((ow >> (i & 31)) & 1u) kw &= ~rw;
        }
        if (tid < 16) keepw_s[tid] = kw;
    }
    __syncthreads();

    // ---- rank kept candidates (order = candidate order = score desc) ----
    if (tid == 0) {
        unsigned s = 0;
        for (int w2 = 0; w2 < 16; ++w2) { wpref[w2] = s; s += __popc(keepw_s[w2]); }
        wpref[16] = s;
    }
    __syncthreads();
    const unsigned nk = wpref[16];

    float* ob = out;                                   // [B,300,4]
    float* os = out + (size_t)B * MAXDET * 4;          // [B,300,1]
    float* ol = os + (size_t)B * MAXDET;               // [B,300,1]
    const int* lb = labels + (size_t)b * N;

    for (int t = tid; t < KPRE; t += nthr) {
        unsigned word = keepw_s[t >> 5];
        if ((word >> (t & 31)) & 1u) {
            unsigned rank = wpref[t >> 5] + __popc(word & ((1u << (t & 31)) - 1u));
            if (rank < MAXDET) {
                float4 bx = boxs[t];
                size_t ro = (size_t)b * MAXDET + rank;
                ob[ro * 4 + 0] = bx.x;
                ob[ro * 4 + 1] = bx.y;
                ob[ro * 4 + 2] = bx.z;
                ob[ro * 4 + 3] = bx.w;
                os[ro] = __uint_as_float(ckey[t]);
                ol[ro] = (float)lb[cidx[t]];
            }
        }
    }
    for (int r = tid; r < MAXDET; r += nthr) {
        if (r >= (int)nk) {
            size_t ro = (size_t)b * MAXDET + r;
            ob[ro * 4 + 0] = -1.f;
            ob[ro * 4 + 1] = -1.f;
            ob[ro * 4 + 2] = -1.f;
            ob[ro * 4 + 3] = -1.f;
            os[ro] = -1.f;
            ol[ro] = -1.f;
        }
    }
}

extern "C" void kernel_launch(void* const* d_in, const int* in_sizes, int n_in,
                              void* d_out, int out_size, void* d_ws, size_t ws_size,
                              hipStream_t stream) {
    const float* anchors = (const float*)d_in[0];
    const float* reg     = (const float*)d_in[1];
    const float* cls     = (const float*)d_in[2];
    const float* sizes   = (const float*)d_in[3];

    const int B = in_sizes[3] / 2;                    // 8
    const int N = in_sizes[0] / (4 * B);              // 200000
    const int C = in_sizes[2] / (B * N);              // 80
    const int total = B * N;

    unsigned* keys = (unsigned*)d_ws;
    int* labels = (int*)((char*)d_ws + (size_t)total * sizeof(unsigned));
    float* out = (float*)d_out;

    dim3 blkA(256);
    dim3 grdA((total + 255) / 256);
    score_label_kernel<<<grdA, blkA, 0, stream>>>(cls, keys, labels, total, C);

    dim3 blkB(1024);
    dim3 grdB(B);
    select_nms_kernel<<<grdB, blkB, 0, stream>>>(anchors, reg, sizes, keys, labels, out, N, B);
}

// Round 3
// 1263.832 us; speedup vs baseline: 1.2030x; 1.2030x over previous
//
#include <hip/hip_runtime.h>
#include <hip/hip_bf16.h>
#include <math.h>

#define KPRE 512
#define CAP 4096
#define MAXDET 300
#define SCORE_THR 0.05f
#define IOU_THR 0.5f
#define APB 64              // anchors per block in kernel A (256 thr = 4 lanes/anchor)
#define HBINS 65536         // per-batch histogram bins

// Monotone 16-bit bin for valid keys: all keys in (bits(0.05), bits(1.0)] have
// (key>>10) in [0xF5334, 0xFE000] -> &0xFFFF strips the constant 0xF0000.
// Granularity = 1024 ulps; bin 0 is reserved for invalid (key==0).
__device__ __forceinline__ unsigned key_bin(unsigned key) {
    return (key >> 10) & 0xFFFFu;
}

// ---------------- Kernel A: per-anchor max/argmax + per-batch global histogram ----------
// 4 consecutive lanes own one anchor; lane q reads float4s q, q+4, ... of the anchor's
// C/4 float4s. Composite (scorebits<<32)|(255-class) makes max == (score desc, class asc).
__global__ __launch_bounds__(256)
void score_label_kernel(const float* __restrict__ cls,
                        unsigned* __restrict__ keys,
                        unsigned char* __restrict__ labels,
                        unsigned* __restrict__ ghist,
                        int N, int C) {
    const int b = blockIdx.y;
    const int tid = threadIdx.x;
    const int g = tid >> 2;                  // anchor within block
    const int q = tid & 3;
    const int a = blockIdx.x * APB + g;
    if (a >= N) return;                      // group-uniform exit (all 4 lanes same a)
    const int F4A = C >> 2;                  // 20

    const float4* p = (const float4*)cls + ((size_t)b * N + a) * F4A;
    unsigned long long best = 0ull;
    for (int f4 = q; f4 < F4A; f4 += 4) {
        float4 v = p[f4];
        int cbase = f4 * 4;
        float m = v.x; int c = cbase;
        if (v.y > m) { m = v.y; c = cbase + 1; }
        if (v.z > m) { m = v.z; c = cbase + 2; }
        if (v.w > m) { m = v.w; c = cbase + 3; }
        unsigned long long comp =
            ((unsigned long long)__float_as_uint(m) << 32) | (unsigned)(255 - c);
        if (comp > best) best = comp;
    }
    // reduce across the 4 lanes of the group (stays within the group under xor 1,2)
    unsigned long long o;
    o = (unsigned long long)__shfl_xor((long long)best, 1, 64); if (o > best) best = o;
    o = (unsigned long long)__shfl_xor((long long)best, 2, 64); if (o > best) best = o;

    if (q == 0) {
        unsigned sb = (unsigned)(best >> 32);
        unsigned cl = 255u - (unsigned)(best & 0xFFFFFFFFull);
        size_t idx = (size_t)b * N + a;
        unsigned key = (__uint_as_float(sb) > SCORE_THR) ? sb : 0u;
        keys[idx] = key;
        labels[idx] = (unsigned char)cl;
        if (key) atomicAdd(&ghist[((size_t)b << 16) + key_bin(key)], 1u);
    }
}

// ---------------- Kernel B: cutoff from histogram + collect + sort + NMS + output -------
__global__ __launch_bounds__(1024, 1)
void select_nms_kernel(const float* __restrict__ anchors,
                       const float* __restrict__ reg,
                       const float* __restrict__ sizes,
                       const unsigned* __restrict__ keys,
                       const unsigned char* __restrict__ labels,
                       const unsigned* __restrict__ ghist,
                       float* __restrict__ out,
                       int N, int B) {
    const int b = blockIdx.x;
    const int tid = threadIdx.x;
    const int nthr = blockDim.x;

    // buf (4096 x u64 = 32KB) aliased later as sup-bitmatrix (512 x 16 x u32 = 32KB)
    __shared__ unsigned long long buf[CAP];
    unsigned* sup = (unsigned*)buf;
    __shared__ float4 boxs[KPRE];
    __shared__ float areas[KPRE];
    __shared__ unsigned ckey[KPRE];
    __shared__ unsigned cidx[KPRE];
    __shared__ unsigned csum[1024];
    __shared__ unsigned validw[16];
    __shared__ unsigned keepw_s[16];
    __shared__ unsigned wpref[17];
    __shared__ unsigned sh_cnt;
    __shared__ int sh_H, sh_M;

    // ---- find cutoff bin H: smallest bin s.t. count(bins >= H) >= 512 ----
    const unsigned* hb = ghist + ((size_t)b << 16);
    {
        unsigned s = 0;
        const uint4* h4 = (const uint4*)hb + (size_t)tid * 16;
        for (int j = 0; j < 16; ++j) { uint4 v = h4[j]; s += v.x + v.y + v.z + v.w; }
        csum[tid] = s;
        __syncthreads();
        for (int off = 1; off < 1024; off <<= 1) {
            unsigned v = csum[tid];
            unsigned w = (tid + off < 1024) ? csum[tid + off] : 0u;
            __syncthreads();
            csum[tid] = v + w;
            __syncthreads();
        }
        if (tid == 0) sh_H = 1;   // fallback: fewer than 512 valid keys -> take all nonzero
        __syncthreads();
        unsigned above = (tid < 1023) ? csum[tid + 1] : 0u;
        if (csum[tid] >= KPRE && above < KPRE) {
            unsigned acc = above;
            int H = tid * 64;
            for (int bin = 63; bin >= 0; --bin) {
                acc += hb[tid * 64 + bin];
                if (acc >= KPRE) { H = tid * 64 + bin; break; }
            }
            sh_H = (H > 0) ? H : 1;
        }
        __syncthreads();
    }
    const unsigned H = (unsigned)sh_H;

    // ---- collect all keys with bin >= H (superset of exact top-512, ~<1.5k here) ----
    if (tid == 0) sh_cnt = 0;
    __syncthreads();
    const unsigned* kb = keys + (size_t)b * N;
    for (int i = tid; i < N; i += nthr) {
        unsigned key = kb[i];
        if (key_bin(key) >= H) {      // key==0 -> bin 0 < H, auto-excluded
            unsigned p = atomicAdd(&sh_cnt, 1u);
            if (p < CAP)
                buf[p] = ((unsigned long long)key << 32) | (unsigned)(~(unsigned)i);
        }
    }
    __syncthreads();
    int cnt = (int)sh_cnt; if (cnt > CAP) cnt = CAP;
    if (tid == 0) {
        int M = KPRE;
        while (M < cnt) M <<= 1;
        sh_M = M;
    }
    __syncthreads();
    const int M = sh_M;
    for (int i2 = cnt + tid; i2 < M; i2 += nthr) buf[i2] = 0ull;
    __syncthreads();

    // ---- bitonic sort descending: key desc, index asc (composite uses ~idx) ----
    for (int kk = 2; kk <= M; kk <<= 1) {
        for (int j = kk >> 1; j > 0; j >>= 1) {
            for (int i2 = tid; i2 < M; i2 += nthr) {
                int l = i2 ^ j;
                if (l > i2) {
                    unsigned long long a = buf[i2], c = buf[l];
                    bool desc = ((i2 & kk) == 0);
                    if (desc ? (a < c) : (a > c)) { buf[i2] = c; buf[l] = a; }
                }
            }
            __syncthreads();
        }
    }

    // ---- extract top-512 candidates; decode + clip boxes (reference formula) ----
    const float wimg = sizes[b * 2 + 1];
    const float himg = sizes[b * 2 + 0];
    for (int t = tid; t < KPRE; t += nthr) {
        unsigned long long c = buf[t];
        unsigned key = (unsigned)(c >> 32);
        unsigned ai = ~(unsigned)(c & 0xFFFFFFFFull);
        bool valid = (key != 0u) && (t < cnt);
        ckey[t] = valid ? key : 0u;
        cidx[t] = valid ? ai : 0u;
        float4 bx = make_float4(0.f, 0.f, 0.f, 0.f);
        if (valid) {
            const float4 a4 = *(const float4*)(anchors + ((size_t)b * N + ai) * 4);
            const float4 r4 = *(const float4*)(reg + ((size_t)b * N + ai) * 4);
            float w = a4.z - a4.x, h = a4.w - a4.y;
            float cx = a4.x + 0.5f * w, cy = a4.y + 0.5f * h;
            float dx = r4.x * 0.1f, dy = r4.y * 0.1f;
            float dw = r4.z * 0.2f, dh = r4.w * 0.2f;
            float pcx = cx + dx * w, pcy = cy + dy * h;
            float pw = expf(dw) * w, ph = expf(dh) * h;
            float x1 = pcx - 0.5f * pw, y1 = pcy - 0.5f * ph;
            float x2 = pcx + 0.5f * pw, y2 = pcy + 0.5f * ph;
            bx.x = fminf(fmaxf(x1, 0.f), wimg);
            bx.y = fminf(fmaxf(y1, 0.f), himg);
            bx.z = fminf(fmaxf(x2, 0.f), wimg);
            bx.w = fminf(fmaxf(y2, 0.f), himg);
        }
        boxs[t] = bx;
        areas[t] = (bx.z - bx.x) * (bx.w - bx.y);
    }
    __syncthreads();

    // ---- suppression bitmatrix: sup[i][w] bit b = (iou(i, w*32+b) > 0.5) && (j > i) ----
    for (int unit = tid; unit < KPRE * 16; unit += nthr) {
        int i = unit >> 4, w = unit & 15;
        float4 bi = boxs[i];
        float ai = areas[i];
        unsigned bits = 0;
        int j0 = w * 32;
        for (int bit = 0; bit < 32; ++bit) {
            int j = j0 + bit;
            if (j > i) {
                float4 bj = boxs[j];
                float ltx = fmaxf(bi.x, bj.x), lty = fmaxf(bi.y, bj.y);
                float rbx = fminf(bi.z, bj.z), rby = fminf(bi.w, bj.w);
                float iw = fmaxf(rbx - ltx, 0.f), ih = fmaxf(rby - lty, 0.f);
                float inter = iw * ih;
                float iou = inter / (ai + areas[j] - inter + 1e-9f);
                if (iou > IOU_THR) bits |= (1u << bit);
            }
        }
        sup[i * 16 + w] = bits;
    }
    __syncthreads();

    // ---- validity bitmask via per-wave ballot ----
    unsigned long long bal = __ballot(tid < KPRE && ckey[tid] != 0u);
    if (tid < KPRE && (tid & 63) == 0) {
        validw[(tid >> 6) * 2] = (unsigned)(bal & 0xFFFFFFFFull);
        validw[(tid >> 6) * 2 + 1] = (unsigned)(bal >> 32);
    }
    __syncthreads();

    // ---- single-wave greedy NMS scan: lane w holds keep-word w in a register ----
    if (tid < 64) {
        unsigned kw = (tid < 16) ? validw[tid] : 0u;
        for (int i = 0; i < KPRE; ++i) {
            unsigned rw = sup[i * 16 + (tid & 15)];
            unsigned ow = __shfl(kw, i >> 5, 64);
            if ((ow >> (i & 31)) & 1u) kw &= ~rw;
        }
        if (tid < 16) keepw_s[tid] = kw;
    }
    __syncthreads();

    // ---- rank kept candidates (order = candidate order = score desc) ----
    if (tid == 0) {
        unsigned s = 0;
        for (int w2 = 0; w2 < 16; ++w2) { wpref[w2] = s; s += __popc(keepw_s[w2]); }
        wpref[16] = s;
    }
    __syncthreads();
    const unsigned nk = wpref[16];

    float* ob = out;                                   // [B,300,4]
    float* os = out + (size_t)B * MAXDET * 4;          // [B,300,1]
    float* ol = os + (size_t)B * MAXDET;               // [B,300,1]
    const unsigned char* lb = labels + (size_t)b * N;

    for (int t = tid; t < KPRE; t += nthr) {
        unsigned word = keepw_s[t >> 5];
        if ((word >> (t & 31)) & 1u) {
            unsigned rank = wpref[t >> 5] + __popc(word & ((1u << (t & 31)) - 1u));
            if (rank < MAXDET) {
                float4 bx = boxs[t];
                size_t ro = (size_t)b * MAXDET + rank;
                ob[ro * 4 + 0] = bx.x;
                ob[ro * 4 + 1] = bx.y;
                ob[ro * 4 + 2] = bx.z;
                ob[ro * 4 + 3] = bx.w;
                os[ro] = __uint_as_float(ckey[t]);
                ol[ro] = (float)lb[cidx[t]];
            }
        }
    }
    for (int r = tid; r < MAXDET; r += nthr) {
        if (r >= (int)nk) {
            size_t ro = (size_t)b * MAXDET + r;
            ob[ro * 4 + 0] = -1.f;
            ob[ro * 4 + 1] = -1.f;
            ob[ro * 4 + 2] = -1.f;
            ob[ro * 4 + 3] = -1.f;
            os[ro] = -1.f;
            ol[ro] = -1.f;
        }
    }
}

extern "C" void kernel_launch(void* const* d_in, const int* in_sizes, int n_in,
                              void* d_out, int out_size, void* d_ws, size_t ws_size,
                              hipStream_t stream) {
    const float* anchors = (const float*)d_in[0];
    const float* reg     = (const float*)d_in[1];
    const float* cls     = (const float*)d_in[2];
    const float* sizes   = (const float*)d_in[3];

    const int B = in_sizes[3] / 2;                    // 8
    const int N = in_sizes[0] / (4 * B);              // 200000
    const int C = in_sizes[2] / (B * N);              // 80
    const int total = B * N;

    // ws layout: keys [total u32] | ghist [B*65536 u32] | labels [total u8]
    unsigned* keys = (unsigned*)d_ws;
    unsigned* ghist = (unsigned*)((char*)d_ws + (size_t)total * 4);
    unsigned char* labels = (unsigned char*)((char*)d_ws + (size_t)total * 4 + (size_t)B * HBINS * 4);
    float* out = (float*)d_out;

    hipMemsetAsync(ghist, 0, (size_t)B * HBINS * 4, stream);

    dim3 blkA(256);
    dim3 grdA((N + APB - 1) / APB, B);
    score_label_kernel<<<grdA, blkA, 0, stream>>>(cls, keys, labels, ghist, N, C);

    dim3 blkB(1024);
    dim3 grdB(B);
    select_nms_kernel<<<grdB, blkB, 0, stream>>>(anchors, reg, sizes, keys, labels, ghist, out, N, B);
}

// Round 4
// 904.013 us; speedup vs baseline: 1.6818x; 1.3980x over previous
//
#include <hip/hip_runtime.h>
#include <hip/hip_bf16.h>
#include <math.h>

#define KPRE 512
#define CAP 4096
#define MAXDET 300
#define SCORE_THR 0.05f
#define IOU_THR 0.5f
#define NREP 16            // LDS histogram replicas (hot-address dilution)

// Monotone 16-bit bin for valid keys: all keys in (bits(0.05), bits(1.0)] have
// (key>>10) in [0xF5334, 0xFE000] -> &0xFFFF strips the constant 0xF0000.
// Granularity = 1024 ulps; bin 0 is reserved for invalid (key==0).
__device__ __forceinline__ unsigned key_bin(unsigned key) {
    return (key >> 10) & 0xFFFFu;
}

// ---------------- Kernel A: pure streaming per-anchor max/argmax (NO atomics) ----------
// 4 consecutive lanes own one anchor; lane q reads float4s q, q+4, ... Composite
// (scorebits<<32)|(255-class) makes max == (score desc, class asc).
template<int F4A>
__global__ __launch_bounds__(256)
void score_label_kernel(const float* __restrict__ cls,
                        unsigned* __restrict__ keys,
                        unsigned char* __restrict__ labels,
                        int N) {
    const int b = blockIdx.y;
    const int tid = threadIdx.x;
    const int g = tid >> 2, q = tid & 3;
    const int a = blockIdx.x * 64 + g;
    if (a >= N) return;                       // 4-lane group uniform
    const float4* p = (const float4*)cls + ((size_t)b * N + a) * F4A;

    float4 vv[F4A / 4];
#pragma unroll
    for (int j = 0; j < F4A / 4; ++j) vv[j] = p[q + 4 * j];   // all loads in flight

    unsigned long long best = 0ull;
#pragma unroll
    for (int j = 0; j < F4A / 4; ++j) {
        float4 v = vv[j];
        int cbase = (q + 4 * j) * 4;
        float m = v.x; int c = cbase;
        if (v.y > m) { m = v.y; c = cbase + 1; }
        if (v.z > m) { m = v.z; c = cbase + 2; }
        if (v.w > m) { m = v.w; c = cbase + 3; }
        unsigned long long comp =
            ((unsigned long long)__float_as_uint(m) << 32) | (unsigned)(255 - c);
        if (comp > best) best = comp;
    }
    unsigned long long o;
    o = (unsigned long long)__shfl_xor((long long)best, 1, 64); if (o > best) best = o;
    o = (unsigned long long)__shfl_xor((long long)best, 2, 64); if (o > best) best = o;

    if (q == 0) {
        unsigned sb = (unsigned)(best >> 32);
        unsigned cl = 255u - (unsigned)(best & 0xFFFFFFFFull);
        size_t idx = (size_t)b * N + a;
        keys[idx] = (__uint_as_float(sb) > SCORE_THR) ? sb : 0u;
        labels[idx] = (unsigned char)cl;
    }
}

__global__ __launch_bounds__(256)
void score_label_generic(const float* __restrict__ cls,
                         unsigned* __restrict__ keys,
                         unsigned char* __restrict__ labels,
                         int N, int C) {
    const int b = blockIdx.y;
    const int tid = threadIdx.x;
    const int g = tid >> 2, q = tid & 3;
    const int a = blockIdx.x * 64 + g;
    if (a >= N) return;
    const int F4A = C >> 2;
    const float4* p = (const float4*)cls + ((size_t)b * N + a) * F4A;
    unsigned long long best = 0ull;
    for (int f4 = q; f4 < F4A; f4 += 4) {
        float4 v = p[f4];
        int cbase = f4 * 4;
        float m = v.x; int c = cbase;
        if (v.y > m) { m = v.y; c = cbase + 1; }
        if (v.z > m) { m = v.z; c = cbase + 2; }
        if (v.w > m) { m = v.w; c = cbase + 3; }
        unsigned long long comp =
            ((unsigned long long)__float_as_uint(m) << 32) | (unsigned)(255 - c);
        if (comp > best) best = comp;
    }
    unsigned long long o;
    o = (unsigned long long)__shfl_xor((long long)best, 1, 64); if (o > best) best = o;
    o = (unsigned long long)__shfl_xor((long long)best, 2, 64); if (o > best) best = o;
    if (q == 0) {
        unsigned sb = (unsigned)(best >> 32);
        unsigned cl = 255u - (unsigned)(best & 0xFFFFFFFFull);
        size_t idx = (size_t)b * N + a;
        keys[idx] = (__uint_as_float(sb) > SCORE_THR) ? sb : 0u;
        labels[idx] = (unsigned char)cl;
    }
}

// ---------------- Kernel B: 2-level LDS-hist select + collect + sort + NMS + output ----
__global__ __launch_bounds__(1024, 1)
void select_nms_kernel(const float* __restrict__ anchors,
                       const float* __restrict__ reg,
                       const float* __restrict__ sizes,
                       const unsigned* __restrict__ keys,
                       const unsigned char* __restrict__ labels,
                       float* __restrict__ out,
                       int N, int B) {
    const int b = blockIdx.x;
    const int tid = threadIdx.x;
    const int nthr = blockDim.x;

    // buf (32KB) aliased: lhist[NREP*256] (16KB) during select; sup[512*16] (32KB) in NMS
    __shared__ __align__(16) unsigned long long buf[CAP];
    unsigned* lhist = (unsigned*)buf;
    unsigned* sup = (unsigned*)buf;
    __shared__ float4 boxs[KPRE];
    __shared__ float areas[KPRE];
    __shared__ unsigned ckey[KPRE];
    __shared__ unsigned cidx[KPRE];
    __shared__ unsigned sscan[256];
    __shared__ unsigned validw[16], keepw_s[16], wpref[17];
    __shared__ unsigned sh_cnt, sh_above, sh_H;
    __shared__ int sh_H1, sh_M;

    const unsigned* kb = keys + (size_t)b * N;
    const uint4* k4 = (const uint4*)kb;
    const int N4 = N >> 2;
    const unsigned rrep = (tid & (NREP - 1)) * 256;

    if (tid == 0) { sh_H1 = -1; sh_cnt = 0; sh_H = 1; }

    // ---- pass 1: coarse hist (bin = key_bin >> 8), NREP-replicated ----
    for (int i = tid; i < 256 * NREP; i += nthr) lhist[i] = 0;
    __syncthreads();
    for (int i = tid; i < N4; i += nthr) {
        uint4 v = k4[i];
        if (v.x) atomicAdd(&lhist[rrep + (key_bin(v.x) >> 8)], 1u);
        if (v.y) atomicAdd(&lhist[rrep + (key_bin(v.y) >> 8)], 1u);
        if (v.z) atomicAdd(&lhist[rrep + (key_bin(v.z) >> 8)], 1u);
        if (v.w) atomicAdd(&lhist[rrep + (key_bin(v.w) >> 8)], 1u);
    }
    for (int i = (N4 << 2) + tid; i < N; i += nthr) {
        unsigned kk = kb[i];
        if (kk) atomicAdd(&lhist[rrep + (key_bin(kk) >> 8)], 1u);
    }
    __syncthreads();
    // merge replicas + Hillis-Steele suffix sum over 256 coarse bins
    if (tid < 256) {
        unsigned s = 0;
        for (int j = 0; j < NREP; ++j) s += lhist[j * 256 + tid];
        sscan[tid] = s;
    }
    __syncthreads();
    for (int off = 1; off < 256; off <<= 1) {
        unsigned v2 = 0;
        if (tid < 256) v2 = sscan[tid] + ((tid + off < 256) ? sscan[tid + off] : 0u);
        __syncthreads();
        if (tid < 256) sscan[tid] = v2;
        __syncthreads();
    }
    if (tid < 256) {
        unsigned above = (tid < 255) ? sscan[tid + 1] : 0u;
        if (sscan[tid] >= KPRE && above < KPRE) { sh_H1 = tid; sh_above = above; }
    }
    __syncthreads();

    // ---- pass 2: fine hist within coarse bin H1 ----
    const int H1 = sh_H1;                      // -1 => fewer than 512 valid -> H = 1
    unsigned H = 1;
    if (H1 >= 0) {
        for (int i = tid; i < 256 * NREP; i += nthr) lhist[i] = 0;
        __syncthreads();
        for (int i = tid; i < N4; i += nthr) {
            uint4 v = k4[i];
            unsigned fb;
            if (v.x) { fb = key_bin(v.x); if ((int)(fb >> 8) == H1) atomicAdd(&lhist[rrep + (fb & 255u)], 1u); }
            if (v.y) { fb = key_bin(v.y); if ((int)(fb >> 8) == H1) atomicAdd(&lhist[rrep + (fb & 255u)], 1u); }
            if (v.z) { fb = key_bin(v.z); if ((int)(fb >> 8) == H1) atomicAdd(&lhist[rrep + (fb & 255u)], 1u); }
            if (v.w) { fb = key_bin(v.w); if ((int)(fb >> 8) == H1) atomicAdd(&lhist[rrep + (fb & 255u)], 1u); }
        }
        for (int i = (N4 << 2) + tid; i < N; i += nthr) {
            unsigned kk = kb[i];
            if (kk) { unsigned fb = key_bin(kk); if ((int)(fb >> 8) == H1) atomicAdd(&lhist[rrep + (fb & 255u)], 1u); }
        }
        __syncthreads();
        if (tid < 256) {
            unsigned s = 0;
            for (int j = 0; j < NREP; ++j) s += lhist[j * 256 + tid];
            sscan[tid] = s;
        }
        __syncthreads();
        for (int off = 1; off < 256; off <<= 1) {
            unsigned v2 = 0;
            if (tid < 256) v2 = sscan[tid] + ((tid + off < 256) ? sscan[tid + off] : 0u);
            __syncthreads();
            if (tid < 256) sscan[tid] = v2;
            __syncthreads();
        }
        if (tid < 256) {
            unsigned abv = ((tid < 255) ? sscan[tid + 1] : 0u) + sh_above;
            if (sscan[tid] + sh_above >= KPRE && abv < KPRE) sh_H = ((unsigned)H1 << 8) + tid;
        }
        __syncthreads();
        H = sh_H; if (H == 0) H = 1;
    }

    // ---- collect all keys with fine bin >= H (superset of exact top-512) ----
    for (int i = tid; i < N4; i += nthr) {
        uint4 v = k4[i];
        unsigned base = (unsigned)(i << 2);
        if (key_bin(v.x) >= H) { unsigned p = atomicAdd(&sh_cnt, 1u); if (p < CAP) buf[p] = ((unsigned long long)v.x << 32) | ~(base); }
        if (key_bin(v.y) >= H) { unsigned p = atomicAdd(&sh_cnt, 1u); if (p < CAP) buf[p] = ((unsigned long long)v.y << 32) | ~(base + 1u); }
        if (key_bin(v.z) >= H) { unsigned p = atomicAdd(&sh_cnt, 1u); if (p < CAP) buf[p] = ((unsigned long long)v.z << 32) | ~(base + 2u); }
        if (key_bin(v.w) >= H) { unsigned p = atomicAdd(&sh_cnt, 1u); if (p < CAP) buf[p] = ((unsigned long long)v.w << 32) | ~(base + 3u); }
    }
    for (int i = (N4 << 2) + tid; i < N; i += nthr) {
        unsigned kk = kb[i];
        if (key_bin(kk) >= H) { unsigned p = atomicAdd(&sh_cnt, 1u); if (p < CAP) buf[p] = ((unsigned long long)kk << 32) | ~((unsigned)i); }
    }
    __syncthreads();
    int cnt = (int)sh_cnt; if (cnt > CAP) cnt = CAP;
    if (tid == 0) {
        int M = KPRE;
        while (M < cnt) M <<= 1;
        sh_M = M;
    }
    __syncthreads();
    const int M = sh_M;
    for (int i2 = cnt + tid; i2 < M; i2 += nthr) buf[i2] = 0ull;
    __syncthreads();

    // ---- bitonic sort descending: key desc, index asc (composite uses ~idx) ----
    for (int kk = 2; kk <= M; kk <<= 1) {
        for (int j = kk >> 1; j > 0; j >>= 1) {
            for (int i2 = tid; i2 < M; i2 += nthr) {
                int l = i2 ^ j;
                if (l > i2) {
                    unsigned long long a = buf[i2], c = buf[l];
                    bool desc = ((i2 & kk) == 0);
                    if (desc ? (a < c) : (a > c)) { buf[i2] = c; buf[l] = a; }
                }
            }
            __syncthreads();
        }
    }

    // ---- extract top-512 candidates; decode + clip boxes (reference formula) ----
    const float wimg = sizes[b * 2 + 1];
    const float himg = sizes[b * 2 + 0];
    for (int t = tid; t < KPRE; t += nthr) {
        unsigned long long c = buf[t];
        unsigned key = (unsigned)(c >> 32);
        unsigned ai = ~(unsigned)(c & 0xFFFFFFFFull);
        bool valid = (key != 0u) && (t < cnt);
        ckey[t] = valid ? key : 0u;
        cidx[t] = valid ? ai : 0u;
        float4 bx = make_float4(0.f, 0.f, 0.f, 0.f);
        if (valid) {
            const float4 a4 = *(const float4*)(anchors + ((size_t)b * N + ai) * 4);
            const float4 r4 = *(const float4*)(reg + ((size_t)b * N + ai) * 4);
            float w = a4.z - a4.x, h = a4.w - a4.y;
            float cx = a4.x + 0.5f * w, cy = a4.y + 0.5f * h;
            float dx = r4.x * 0.1f, dy = r4.y * 0.1f;
            float dw = r4.z * 0.2f, dh = r4.w * 0.2f;
            float pcx = cx + dx * w, pcy = cy + dy * h;
            float pw = expf(dw) * w, ph = expf(dh) * h;
            float x1 = pcx - 0.5f * pw, y1 = pcy - 0.5f * ph;
            float x2 = pcx + 0.5f * pw, y2 = pcy + 0.5f * ph;
            bx.x = fminf(fmaxf(x1, 0.f), wimg);
            bx.y = fminf(fmaxf(y1, 0.f), himg);
            bx.z = fminf(fmaxf(x2, 0.f), wimg);
            bx.w = fminf(fmaxf(y2, 0.f), himg);
        }
        boxs[t] = bx;
        areas[t] = (bx.z - bx.x) * (bx.w - bx.y);
    }
    __syncthreads();

    // ---- suppression bitmatrix: sup[i][w] bit b = (iou(i, w*32+b) > 0.5) && (j > i) ----
    for (int unit = tid; unit < KPRE * 16; unit += nthr) {
        int i = unit >> 4, w = unit & 15;
        float4 bi = boxs[i];
        float ai = areas[i];
        unsigned bits = 0;
        int j0 = w * 32;
        for (int bit = 0; bit < 32; ++bit) {
            int j = j0 + bit;
            if (j > i) {
                float4 bj = boxs[j];
                float ltx = fmaxf(bi.x, bj.x), lty = fmaxf(bi.y, bj.y);
                float rbx = fminf(bi.z, bj.z), rby = fminf(bi.w, bj.w);
                float iw = fmaxf(rbx - ltx, 0.f), ih = fmaxf(rby - lty, 0.f);
                float inter = iw * ih;
                float iou = inter / (ai + areas[j] - inter + 1e-9f);
                if (iou > IOU_THR) bits |= (1u << bit);
            }
        }
        sup[i * 16 + w] = bits;
    }
    __syncthreads();

    // ---- validity bitmask via per-wave ballot ----
    unsigned long long bal = __ballot(tid < KPRE && ckey[tid] != 0u);
    if (tid < KPRE && (tid & 63) == 0) {
        validw[(tid >> 6) * 2] = (unsigned)(bal & 0xFFFFFFFFull);
        validw[(tid >> 6) * 2 + 1] = (unsigned)(bal >> 32);
    }
    __syncthreads();

    // ---- single-wave greedy NMS scan: lane w holds keep-word w in a register ----
    if (tid < 64) {
        unsigned kw = (tid < 16) ? validw[tid] : 0u;
        for (int i = 0; i < KPRE; ++i) {
            unsigned rw = sup[i * 16 + (tid & 15)];
            unsigned ow = __shfl(kw, i >> 5, 64);
            if ((ow >> (i & 31)) & 1u) kw &= ~rw;
        }
        if (tid < 16) keepw_s[tid] = kw;
    }
    __syncthreads();

    // ---- rank kept candidates (order = candidate order = score desc) ----
    if (tid == 0) {
        unsigned s = 0;
        for (int w2 = 0; w2 < 16; ++w2) { wpref[w2] = s; s += __popc(keepw_s[w2]); }
        wpref[16] = s;
    }
    __syncthreads();
    const unsigned nk = wpref[16];

    float* ob = out;                                   // [B,300,4]
    float* os = out + (size_t)B * MAXDET * 4;          // [B,300,1]
    float* ol = os + (size_t)B * MAXDET;               // [B,300,1]
    const unsigned char* lb = labels + (size_t)b * N;

    for (int t = tid; t < KPRE; t += nthr) {
        unsigned word = keepw_s[t >> 5];
        if ((word >> (t & 31)) & 1u) {
            unsigned rank = wpref[t >> 5] + __popc(word & ((1u << (t & 31)) - 1u));
            if (rank < MAXDET) {
                float4 bx = boxs[t];
                size_t ro = (size_t)b * MAXDET + rank;
                ob[ro * 4 + 0] = bx.x;
                ob[ro * 4 + 1] = bx.y;
                ob[ro * 4 + 2] = bx.z;
                ob[ro * 4 + 3] = bx.w;
                os[ro] = __uint_as_float(ckey[t]);
                ol[ro] = (float)lb[cidx[t]];
            }
        }
    }
    for (int r = tid; r < MAXDET; r += nthr) {
        if (r >= (int)nk) {
            size_t ro = (size_t)b * MAXDET + r;
            ob[ro * 4 + 0] = -1.f;
            ob[ro * 4 + 1] = -1.f;
            ob[ro * 4 + 2] = -1.f;
            ob[ro * 4 + 3] = -1.f;
            os[ro] = -1.f;
            ol[ro] = -1.f;
        }
    }
}

extern "C" void kernel_launch(void* const* d_in, const int* in_sizes, int n_in,
                              void* d_out, int out_size, void* d_ws, size_t ws_size,
                              hipStream_t stream) {
    const float* anchors = (const float*)d_in[0];
    const float* reg     = (const float*)d_in[1];
    const float* cls     = (const float*)d_in[2];
    const float* sizes   = (const float*)d_in[3];

    const int B = in_sizes[3] / 2;                    // 8
    const int N = in_sizes[0] / (4 * B);              // 200000
    const int C = in_sizes[2] / (B * N);              // 80
    const int total = B * N;

    // ws layout: keys [total u32] | labels [total u8]
    unsigned* keys = (unsigned*)d_ws;
    unsigned char* labels = (unsigned char*)((char*)d_ws + (size_t)total * 4);
    float* out = (float*)d_out;

    dim3 blkA(256);
    dim3 grdA((N + 63) / 64, B);
    if (C == 80)
        score_label_kernel<20><<<grdA, blkA, 0, stream>>>(cls, keys, labels, N);
    else
        score_label_generic<<<grdA, blkA, 0, stream>>>(cls, keys, labels, N, C);

    select_nms_kernel<<<dim3(B), dim3(1024), 0, stream>>>(anchors, reg, sizes, keys, labels, out, N, B);
}